// Round 1
// baseline (925.656 us; speedup 1.0000x reference)
//
#include <hip/hip_runtime.h>

// NeuralSumProductModel: weighted sum-product LDPC decoder.
// N=8192 vars, M=4096 checks, DV=3, DC=6, ITERS=5, B=1024, E=24576.
// One block per batch row; thread t owns 24 contiguous edges = 8 variables,
// messages stay in registers. Check-node reduction via LDS atomics
// (chk_sum f32 log2-magnitudes, chk_par int neg-counts), LOO by subtraction.

#define N_VARS 8192
#define M_CHK  4096
#define ITERS  5
#define BATCH  1024
#define NEDGE  (N_VARS * 3)     // 24576
#define TPB    1024
#define EPT    (NEDGE / TPB)    // 24 edges / thread
#define VPT    (N_VARS / TPB)   // 8 variables / thread

#define LOG2E_F 1.44269504f
#define LN2_F   0.69314718f
#define M_CLIP  39.863137f      // -log2(1e-12)
#define E_CLIP  0.99999988f     // float32(1 - 1e-7)

// Compute stored message for edge with input x: m = -log2|tanh(x/2)| (>=0),
// sign bit = (x<0). Scatter m and neg into the check accumulators.
__device__ __forceinline__ float edge_msg(float x, int c,
                                          float* __restrict__ chk_sum,
                                          int* __restrict__ chk_par) {
    float a  = fabsf(x);
    float ee = __builtin_amdgcn_exp2f(-a * LOG2E_F);          // e^{-|x|}
    // -log2(tanh(|x|/2)) = log2(1+e) - log2(1-e)  (>= 0)
    float m  = __builtin_amdgcn_logf(1.0f + ee) - __builtin_amdgcn_logf(1.0f - ee);
    m = fminf(m, M_CLIP);                                      // clip |t| >= 1e-12
    unsigned neg = (x < 0.0f) ? 1u : 0u;
    atomicAdd(&chk_sum[c], m);
    atomicAdd(&chk_par[c], (int)neg);
    return __uint_as_float(__float_as_uint(m) | (neg << 31));
}

__global__ __launch_bounds__(TPB)
void nsp_kernel(const float* __restrict__ llr,
                const float* __restrict__ vw,
                const float* __restrict__ cw,
                const int*   __restrict__ chk_idx,
                float* __restrict__ out)
{
    __shared__ float chk_sum[M_CHK];
    __shared__ int   chk_par[M_CHK];

    const int b  = blockIdx.x;
    const int t  = threadIdx.x;
    const int e0 = t * EPT;   // first owned edge (variable-major layout)
    const int n0 = t * VPT;   // first owned variable

    // llr values for my 8 variables (kept in registers for all iterations)
    float llr_v[VPT];
    {
        const float4* p = (const float4*)(llr + (size_t)b * N_VARS + n0);
        float4 a = p[0], c = p[1];
        llr_v[0] = a.x; llr_v[1] = a.y; llr_v[2] = a.z; llr_v[3] = a.w;
        llr_v[4] = c.x; llr_v[5] = c.y; llr_v[6] = c.z; llr_v[7] = c.w;
    }

    // check indices of my 24 edges, packed 2x16b per reg (values < 4096)
    unsigned pc[EPT / 2];
    {
        const int4* p = (const int4*)(chk_idx + e0);
#pragma unroll
        for (int k = 0; k < EPT / 4; ++k) {
            int4 v = p[k];
            pc[2 * k]     = (unsigned)v.x | ((unsigned)v.y << 16);
            pc[2 * k + 1] = (unsigned)v.z | ((unsigned)v.w << 16);
        }
    }

    float st[EPT];   // per-edge state: Phase A -> packed (m,neg); Phase B -> signed message

    for (int it = 0; it < ITERS; ++it) {
        // ---- zero check accumulators ----
#pragma unroll
        for (int k = 0; k < M_CHK / TPB; ++k) {
            chk_sum[t + k * TPB] = 0.0f;
            chk_par[t + k * TPB] = 0;
        }
        __syncthreads();

        // ---- Phase A: variable node (LOO over DV=3) + tanh/log + scatter ----
        if (it == 0) {
            // ext == 0  =>  a_priori == 0  =>  x = llr[n] for all 3 edges
#pragma unroll
            for (int v = 0; v < VPT; ++v) {
                float xl = llr_v[v];
#pragma unroll
                for (int j = 0; j < 3; ++j) {
                    int e = 3 * v + j;
                    int c = (pc[e >> 1] >> ((e & 1) * 16)) & 0xFFFF;
                    st[e] = edge_msg(xl, c, chk_sum, chk_par);
                }
            }
        } else {
            const float* cwr = cw + (size_t)(it - 1) * NEDGE + e0;
            const float* vwr = vw + (size_t)it * NEDGE + e0;
            float outb[VPT];
#pragma unroll
            for (int v = 0; v < VPT; ++v) {
                // ext = raw check msg * cnode_w[it-1]
                float x0 = st[3 * v]     * cwr[3 * v];
                float x1 = st[3 * v + 1] * cwr[3 * v + 1];
                float x2 = st[3 * v + 2] * cwr[3 * v + 2];
                float s  = x0 + x1 + x2;
                outb[v]  = s + llr_v[v];             // output row it-1 (fused)
#pragma unroll
                for (int j = 0; j < 3; ++j) {
                    int e  = 3 * v + j;
                    float extj = (j == 0) ? x0 : (j == 1) ? x1 : x2;
                    float x = (s - extj) * vwr[e - 3 * v + 3 * v] + llr_v[v]; // vwr[e]
                    x = (s - extj) * vwr[e] + llr_v[v];
                    int c = (pc[e >> 1] >> ((e & 1) * 16)) & 0xFFFF;
                    st[e] = edge_msg(x, c, chk_sum, chk_par);
                }
            }
            float* op = out + ((size_t)(it - 1) * BATCH + b) * N_VARS + n0;
            ((float4*)op)[0] = make_float4(outb[0], outb[1], outb[2], outb[3]);
            ((float4*)op)[1] = make_float4(outb[4], outb[5], outb[6], outb[7]);
        }
        __syncthreads();

        // ---- Phase B: check node LOO + 2*atanh, in-register update ----
#pragma unroll
        for (int e = 0; e < EPT; ++e) {
            unsigned u = __float_as_uint(st[e]);
            float m  = __uint_as_float(u & 0x7fffffffu);
            int  neg = (int)(u >> 31);
            int  c   = (pc[e >> 1] >> ((e & 1) * 16)) & 0xFFFF;
            float S  = chk_sum[c];
            int   P  = chk_par[c];
            float E  = __builtin_amdgcn_exp2f(m - S);       // prod of other |t|
            E = fminf(E, E_CLIP);                            // clip to 1-1e-7
            float r = LN2_F * (__builtin_amdgcn_logf(1.0f + E)
                             - __builtin_amdgcn_logf(1.0f - E)); // 2*atanh(E)
            if ((P - neg) & 1) r = -r;                       // LOO parity sign
            st[e] = r;                                       // raw check msg
        }
        __syncthreads();
    }

    // ---- final output row (iter ITERS-1), ext = msg * cnode_w[ITERS-1] ----
    {
        const float* cwr = cw + (size_t)(ITERS - 1) * NEDGE + e0;
        float outb[VPT];
#pragma unroll
        for (int v = 0; v < VPT; ++v) {
            float s = st[3 * v]     * cwr[3 * v]
                    + st[3 * v + 1] * cwr[3 * v + 1]
                    + st[3 * v + 2] * cwr[3 * v + 2];
            outb[v] = s + llr_v[v];
        }
        float* op = out + ((size_t)(ITERS - 1) * BATCH + b) * N_VARS + n0;
        ((float4*)op)[0] = make_float4(outb[0], outb[1], outb[2], outb[3]);
        ((float4*)op)[1] = make_float4(outb[4], outb[5], outb[6], outb[7]);
    }
}

extern "C" void kernel_launch(void* const* d_in, const int* in_sizes, int n_in,
                              void* d_out, int out_size, void* d_ws, size_t ws_size,
                              hipStream_t stream) {
    const float* llr = (const float*)d_in[0];   // (B, N)
    const float* vw  = (const float*)d_in[1];   // (ITERS, E)
    const float* cw  = (const float*)d_in[2];   // (ITERS, E)
    // d_in[3] = var_idx (unused: edges are variable-major, var = e/3)
    const int*   chk = (const int*)d_in[4];     // (E,)
    // d_in[5] = n_checks scalar (M_CHK compile-time)
    float* out = (float*)d_out;                 // (ITERS, B, N) f32

    nsp_kernel<<<BATCH, TPB, 0, stream>>>(llr, vw, cw, chk, out);
}

// Round 2
// 395.466 us; speedup vs baseline: 2.3407x; 2.3407x over previous
//
#include <hip/hip_runtime.h>

// NeuralSumProductModel: weighted sum-product LDPC decoder.
// N=8192 vars, M=4096 checks, DV=3, DC=6, ITERS=5, B=1024, E=24576.
// One block per batch row; thread t owns 24 contiguous edges = 8 variables,
// messages stay in registers. Check reduction WITHOUT atomics:
//   setup kernel builds addr[e] = c*6 + slot (slot = rank of edge within its
//   check); Phase A plain-scatter-writes packed messages to lds_m[addr];
//   Phase A2 (4 checks/thread) reduces 6 contiguous slots -> packed chk_tot;
//   Phase B reads one packed word per edge. 2 barriers/iter, no zeroing.

#define N_VARS 8192
#define M_CHK  4096
#define ITERS  5
#define BATCH  1024
#define NEDGE  (N_VARS * 3)     // 24576
#define TPB    1024
#define EPT    (NEDGE / TPB)    // 24 edges / thread
#define VPT    (N_VARS / TPB)   // 8 variables / thread
#define CPT    (M_CHK / TPB)    // 4 checks / thread

#define LOG2E_F 1.44269504f
#define LN2_F   0.69314718f
#define M_CLIP  39.863137f      // -log2(1e-12)
#define E_CLIP  0.99999988f     // float32(1 - 1e-7)

// packed edge message: bits[30:0] = m = -log2|tanh(x/2)| (>=0), bit31 = (x<0)
__device__ __forceinline__ float edge_msg(float x) {
    float a  = fabsf(x);
    float ee = __builtin_amdgcn_exp2f(-a * LOG2E_F);          // e^{-|x|}
    float m  = __builtin_amdgcn_logf(1.0f + ee) - __builtin_amdgcn_logf(1.0f - ee);
    m = fminf(m, M_CLIP);
    unsigned neg = (x < 0.0f) ? 0x80000000u : 0u;
    return __uint_as_float(__float_as_uint(m) | neg);
}

// ---- setup: per-edge slot within its check (order irrelevant, just distinct)
__global__ void setup_slots(const int* __restrict__ chk,
                            unsigned* __restrict__ tbl,
                            int* __restrict__ cnt) {
    int e = blockIdx.x * 256 + threadIdx.x;
    if (e < NEDGE) {
        int c = chk[e];
        int slot = atomicAdd(&cnt[c], 1);
        tbl[e] = ((unsigned)c << 16) | (unsigned)(c * 6 + slot);
    }
}

__global__ __launch_bounds__(TPB)
void nsp_kernel(const float* __restrict__ llr,
                const float* __restrict__ vw,
                const float* __restrict__ cw,
                const unsigned* __restrict__ tbl,
                float* __restrict__ out)
{
    __shared__ float    lds_m[NEDGE];     // 96 KB: packed msgs at c*6+slot
    __shared__ unsigned chk_tot[M_CHK];   // 16 KB: packed (S, parity)

    const int b  = blockIdx.x;
    const int t  = threadIdx.x;
    const int e0 = t * EPT;
    const int n0 = t * VPT;
    const int c0 = t * CPT;

    // llr for my 8 variables
    float llr_v[VPT];
    {
        const float4* p = (const float4*)(llr + (size_t)b * N_VARS + n0);
        float4 a = p[0], c = p[1];
        llr_v[0] = a.x; llr_v[1] = a.y; llr_v[2] = a.z; llr_v[3] = a.w;
        llr_v[4] = c.x; llr_v[5] = c.y; llr_v[6] = c.z; llr_v[7] = c.w;
    }

    // per-edge (c<<16 | lds_addr) for my 24 edges
    unsigned te[EPT];
    {
        const uint4* p = (const uint4*)(tbl + e0);
#pragma unroll
        for (int k = 0; k < EPT / 4; ++k) {
            uint4 v = p[k];
            te[4 * k]     = v.x;
            te[4 * k + 1] = v.y;
            te[4 * k + 2] = v.z;
            te[4 * k + 3] = v.w;
        }
    }

    float st[EPT];   // Phase A -> packed (m,sign); Phase B -> signed message

    for (int it = 0; it < ITERS; ++it) {
        // ---- Phase A: variable node LOO + log-domain msg + scatter to LDS
        if (it == 0) {
#pragma unroll
            for (int v = 0; v < VPT; ++v) {
                float p = edge_msg(llr_v[v]);      // ext==0: same msg on 3 edges
#pragma unroll
                for (int j = 0; j < 3; ++j) {
                    int e = 3 * v + j;
                    st[e] = p;
                    lds_m[te[e] & 0xFFFFu] = p;
                }
            }
        } else {
            const float* cwr = cw + (size_t)(it - 1) * NEDGE + e0;
            const float* vwr = vw + (size_t)it * NEDGE + e0;
            float outb[VPT];
#pragma unroll
            for (int v = 0; v < VPT; ++v) {
                float x0 = st[3 * v]     * cwr[3 * v];
                float x1 = st[3 * v + 1] * cwr[3 * v + 1];
                float x2 = st[3 * v + 2] * cwr[3 * v + 2];
                float s  = x0 + x1 + x2;
                outb[v]  = s + llr_v[v];           // output row it-1 (fused)
#pragma unroll
                for (int j = 0; j < 3; ++j) {
                    int e = 3 * v + j;
                    float extj = (j == 0) ? x0 : (j == 1) ? x1 : x2;
                    float x = (s - extj) * vwr[e] + llr_v[v];
                    float p = edge_msg(x);
                    st[e] = p;
                    lds_m[te[e] & 0xFFFFu] = p;
                }
            }
            float* op = out + ((size_t)(it - 1) * BATCH + b) * N_VARS + n0;
            ((float4*)op)[0] = make_float4(outb[0], outb[1], outb[2], outb[3]);
            ((float4*)op)[1] = make_float4(outb[4], outb[5], outb[6], outb[7]);
        }
        __syncthreads();

        // ---- Phase A2: per-check reduction (4 checks/thread, contiguous)
#pragma unroll
        for (int k = 0; k < CPT; ++k) {
            int c = c0 + k;
            const float2* q = (const float2*)(lds_m + c * 6);   // 8B-aligned
            float2 q0 = q[0], q1 = q[1], q2 = q[2];
            unsigned u0 = __float_as_uint(q0.x), u1 = __float_as_uint(q0.y);
            unsigned u2 = __float_as_uint(q1.x), u3 = __float_as_uint(q1.y);
            unsigned u4 = __float_as_uint(q2.x), u5 = __float_as_uint(q2.y);
            float S = __uint_as_float(u0 & 0x7fffffffu)
                    + __uint_as_float(u1 & 0x7fffffffu)
                    + __uint_as_float(u2 & 0x7fffffffu)
                    + __uint_as_float(u3 & 0x7fffffffu)
                    + __uint_as_float(u4 & 0x7fffffffu)
                    + __uint_as_float(u5 & 0x7fffffffu);
            unsigned P = (u0 ^ u1 ^ u2 ^ u3 ^ u4 ^ u5) & 0x80000000u;
            chk_tot[c] = __float_as_uint(S) | P;   // S>=0 so bit31 free
        }
        __syncthreads();

        // ---- Phase B: per-edge LOO + 2*atanh
#pragma unroll
        for (int e = 0; e < EPT; ++e) {
            unsigned u = __float_as_uint(st[e]);
            float m  = __uint_as_float(u & 0x7fffffffu);
            unsigned c = te[e] >> 16;
            unsigned T = chk_tot[c];
            float S  = __uint_as_float(T & 0x7fffffffu);
            unsigned P = (T ^ u) & 0x80000000u;     // LOO parity
            float E = __builtin_amdgcn_exp2f(m - S); // prod of other |t|
            E = fminf(E, E_CLIP);
            float r = LN2_F * (__builtin_amdgcn_logf(1.0f + E)
                             - __builtin_amdgcn_logf(1.0f - E)); // 2*atanh
            st[e] = __uint_as_float(__float_as_uint(r) ^ P);
        }
        // no barrier needed: next Phase A writes lds_m, whose last readers
        // (Phase A2) are already past the A2->B barrier; chk_tot's next
        // writer (A2') is behind next iter's A->A2 barrier.
    }

    // ---- final output row: ext = msg * cnode_w[ITERS-1]
    {
        const float* cwr = cw + (size_t)(ITERS - 1) * NEDGE + e0;
        float outb[VPT];
#pragma unroll
        for (int v = 0; v < VPT; ++v) {
            float s = st[3 * v]     * cwr[3 * v]
                    + st[3 * v + 1] * cwr[3 * v + 1]
                    + st[3 * v + 2] * cwr[3 * v + 2];
            outb[v] = s + llr_v[v];
        }
        float* op = out + ((size_t)(ITERS - 1) * BATCH + b) * N_VARS + n0;
        ((float4*)op)[0] = make_float4(outb[0], outb[1], outb[2], outb[3]);
        ((float4*)op)[1] = make_float4(outb[4], outb[5], outb[6], outb[7]);
    }
}

extern "C" void kernel_launch(void* const* d_in, const int* in_sizes, int n_in,
                              void* d_out, int out_size, void* d_ws, size_t ws_size,
                              hipStream_t stream) {
    const float* llr = (const float*)d_in[0];   // (B, N)
    const float* vw  = (const float*)d_in[1];   // (ITERS, E)
    const float* cw  = (const float*)d_in[2];   // (ITERS, E)
    // d_in[3] = var_idx (unused: edges are variable-major, var = e/3)
    const int*   chk = (const int*)d_in[4];     // (E,)
    float* out = (float*)d_out;                 // (ITERS, B, N) f32

    // ws layout: [0, 96KB) u32 tbl[NEDGE]; [96KB, +16KB) int cnt[M_CHK]
    unsigned* tbl = (unsigned*)d_ws;
    int*      cnt = (int*)((char*)d_ws + NEDGE * sizeof(unsigned));

    hipMemsetAsync(cnt, 0, M_CHK * sizeof(int), stream);
    setup_slots<<<(NEDGE + 255) / 256, 256, 0, stream>>>(chk, tbl, cnt);
    nsp_kernel<<<BATCH, TPB, 0, stream>>>(llr, vw, cw, tbl, out);
}

// Round 3
// 394.572 us; speedup vs baseline: 2.3460x; 1.0023x over previous
//
#include <hip/hip_runtime.h>

// NeuralSumProductModel: weighted sum-product LDPC decoder.
// N=8192 vars, M=4096 checks, DV=3, DC=6, ITERS=5, B=1024, E=24576.
// One block per batch row; thread t owns 24 contiguous edges = 8 variables,
// messages stay in registers. Check reduction WITHOUT atomics:
//   setup kernel builds addr[e] = c*6 + slot (slot = rank of edge within its
//   check); Phase A plain-scatter-writes packed messages to lds_m[addr];
//   Phase A2 (4 checks/thread) reduces 6 contiguous slots -> packed chk_tot;
//   Phase B reads one packed word per edge. 2 barriers/iter, no zeroing.
// __launch_bounds__(1024,4): LDS (112KB) caps us at 1 block/CU = 4 waves/EU
// anyway; request exactly that so the allocator gets 128 VGPRs and the
// st[]/te[] arrays stay in registers (at the default VGPR=64 they spilled to
// scratch -> +127MB HBM fetch, +100MB write).

#define N_VARS 8192
#define M_CHK  4096
#define ITERS  5
#define BATCH  1024
#define NEDGE  (N_VARS * 3)     // 24576
#define TPB    1024
#define EPT    (NEDGE / TPB)    // 24 edges / thread
#define VPT    (N_VARS / TPB)   // 8 variables / thread
#define CPT    (M_CHK / TPB)    // 4 checks / thread

#define LOG2E_F 1.44269504f
#define LN2_F   0.69314718f
#define M_CLIP  39.863137f      // -log2(1e-12)
#define E_CLIP  0.99999988f     // float32(1 - 1e-7)

// packed edge message: bits[30:0] = m = -log2|tanh(x/2)| (>=0), bit31 = (x<0)
__device__ __forceinline__ float edge_msg(float x) {
    float a  = fabsf(x);
    float ee = __builtin_amdgcn_exp2f(-a * LOG2E_F);          // e^{-|x|}
    float m  = __builtin_amdgcn_logf(1.0f + ee) - __builtin_amdgcn_logf(1.0f - ee);
    m = fminf(m, M_CLIP);
    unsigned neg = (x < 0.0f) ? 0x80000000u : 0u;
    return __uint_as_float(__float_as_uint(m) | neg);
}

// ---- setup: per-edge slot within its check (order irrelevant, just distinct)
__global__ void setup_slots(const int* __restrict__ chk,
                            unsigned* __restrict__ tbl,
                            int* __restrict__ cnt) {
    int e = blockIdx.x * 256 + threadIdx.x;
    if (e < NEDGE) {
        int c = chk[e];
        int slot = atomicAdd(&cnt[c], 1);
        tbl[e] = ((unsigned)c << 16) | (unsigned)(c * 6 + slot);
    }
}

__global__ __launch_bounds__(TPB, 4)
void nsp_kernel(const float* __restrict__ llr,
                const float* __restrict__ vw,
                const float* __restrict__ cw,
                const unsigned* __restrict__ tbl,
                float* __restrict__ out)
{
    __shared__ float    lds_m[NEDGE];     // 96 KB: packed msgs at c*6+slot
    __shared__ unsigned chk_tot[M_CHK];   // 16 KB: packed (S, parity)

    const int b  = blockIdx.x;
    const int t  = threadIdx.x;
    const int e0 = t * EPT;
    const int n0 = t * VPT;
    const int c0 = t * CPT;

    // llr for my 8 variables
    float llr_v[VPT];
    {
        const float4* p = (const float4*)(llr + (size_t)b * N_VARS + n0);
        float4 a = p[0], c = p[1];
        llr_v[0] = a.x; llr_v[1] = a.y; llr_v[2] = a.z; llr_v[3] = a.w;
        llr_v[4] = c.x; llr_v[5] = c.y; llr_v[6] = c.z; llr_v[7] = c.w;
    }

    // per-edge (c<<16 | lds_addr) for my 24 edges
    unsigned te[EPT];
    {
        const uint4* p = (const uint4*)(tbl + e0);
#pragma unroll
        for (int k = 0; k < EPT / 4; ++k) {
            uint4 v = p[k];
            te[4 * k]     = v.x;
            te[4 * k + 1] = v.y;
            te[4 * k + 2] = v.z;
            te[4 * k + 3] = v.w;
        }
    }

    float st[EPT];   // Phase A -> packed (m,sign); Phase B -> signed message

    for (int it = 0; it < ITERS; ++it) {
        // ---- Phase A: variable node LOO + log-domain msg + scatter to LDS
        if (it == 0) {
#pragma unroll
            for (int v = 0; v < VPT; ++v) {
                float p = edge_msg(llr_v[v]);      // ext==0: same msg on 3 edges
#pragma unroll
                for (int j = 0; j < 3; ++j) {
                    int e = 3 * v + j;
                    st[e] = p;
                    lds_m[te[e] & 0xFFFFu] = p;
                }
            }
        } else {
            const float* cwr = cw + (size_t)(it - 1) * NEDGE + e0;
            const float* vwr = vw + (size_t)it * NEDGE + e0;
            float outb[VPT];
#pragma unroll
            for (int v = 0; v < VPT; ++v) {
                float x0 = st[3 * v]     * cwr[3 * v];
                float x1 = st[3 * v + 1] * cwr[3 * v + 1];
                float x2 = st[3 * v + 2] * cwr[3 * v + 2];
                float s  = x0 + x1 + x2;
                outb[v]  = s + llr_v[v];           // output row it-1 (fused)
#pragma unroll
                for (int j = 0; j < 3; ++j) {
                    int e = 3 * v + j;
                    float extj = (j == 0) ? x0 : (j == 1) ? x1 : x2;
                    float x = (s - extj) * vwr[e] + llr_v[v];
                    float p = edge_msg(x);
                    st[e] = p;
                    lds_m[te[e] & 0xFFFFu] = p;
                }
            }
            float* op = out + ((size_t)(it - 1) * BATCH + b) * N_VARS + n0;
            ((float4*)op)[0] = make_float4(outb[0], outb[1], outb[2], outb[3]);
            ((float4*)op)[1] = make_float4(outb[4], outb[5], outb[6], outb[7]);
        }
        __syncthreads();

        // ---- Phase A2: per-check reduction (4 checks/thread, contiguous)
#pragma unroll
        for (int k = 0; k < CPT; ++k) {
            int c = c0 + k;
            const float2* q = (const float2*)(lds_m + c * 6);   // 8B-aligned
            float2 q0 = q[0], q1 = q[1], q2 = q[2];
            unsigned u0 = __float_as_uint(q0.x), u1 = __float_as_uint(q0.y);
            unsigned u2 = __float_as_uint(q1.x), u3 = __float_as_uint(q1.y);
            unsigned u4 = __float_as_uint(q2.x), u5 = __float_as_uint(q2.y);
            float S = __uint_as_float(u0 & 0x7fffffffu)
                    + __uint_as_float(u1 & 0x7fffffffu)
                    + __uint_as_float(u2 & 0x7fffffffu)
                    + __uint_as_float(u3 & 0x7fffffffu)
                    + __uint_as_float(u4 & 0x7fffffffu)
                    + __uint_as_float(u5 & 0x7fffffffu);
            unsigned P = (u0 ^ u1 ^ u2 ^ u3 ^ u4 ^ u5) & 0x80000000u;
            chk_tot[c] = __float_as_uint(S) | P;   // S>=0 so bit31 free
        }
        __syncthreads();

        // ---- Phase B: per-edge LOO + 2*atanh
#pragma unroll
        for (int e = 0; e < EPT; ++e) {
            unsigned u = __float_as_uint(st[e]);
            float m  = __uint_as_float(u & 0x7fffffffu);
            unsigned c = te[e] >> 16;
            unsigned T = chk_tot[c];
            float S  = __uint_as_float(T & 0x7fffffffu);
            unsigned P = (T ^ u) & 0x80000000u;     // LOO parity
            float E = __builtin_amdgcn_exp2f(m - S); // prod of other |t|
            E = fminf(E, E_CLIP);
            float r = LN2_F * (__builtin_amdgcn_logf(1.0f + E)
                             - __builtin_amdgcn_logf(1.0f - E)); // 2*atanh
            st[e] = __uint_as_float(__float_as_uint(r) ^ P);
        }
        // no barrier needed: next Phase A writes lds_m, whose last readers
        // (Phase A2) are already past the A2->B barrier; chk_tot's next
        // writer (A2') is behind next iter's A->A2 barrier.
    }

    // ---- final output row: ext = msg * cnode_w[ITERS-1]
    {
        const float* cwr = cw + (size_t)(ITERS - 1) * NEDGE + e0;
        float outb[VPT];
#pragma unroll
        for (int v = 0; v < VPT; ++v) {
            float s = st[3 * v]     * cwr[3 * v]
                    + st[3 * v + 1] * cwr[3 * v + 1]
                    + st[3 * v + 2] * cwr[3 * v + 2];
            outb[v] = s + llr_v[v];
        }
        float* op = out + ((size_t)(ITERS - 1) * BATCH + b) * N_VARS + n0;
        ((float4*)op)[0] = make_float4(outb[0], outb[1], outb[2], outb[3]);
        ((float4*)op)[1] = make_float4(outb[4], outb[5], outb[6], outb[7]);
    }
}

extern "C" void kernel_launch(void* const* d_in, const int* in_sizes, int n_in,
                              void* d_out, int out_size, void* d_ws, size_t ws_size,
                              hipStream_t stream) {
    const float* llr = (const float*)d_in[0];   // (B, N)
    const float* vw  = (const float*)d_in[1];   // (ITERS, E)
    const float* cw  = (const float*)d_in[2];   // (ITERS, E)
    // d_in[3] = var_idx (unused: edges are variable-major, var = e/3)
    const int*   chk = (const int*)d_in[4];     // (E,)
    float* out = (float*)d_out;                 // (ITERS, B, N) f32

    // ws layout: [0, 96KB) u32 tbl[NEDGE]; [96KB, +16KB) int cnt[M_CHK]
    unsigned* tbl = (unsigned*)d_ws;
    int*      cnt = (int*)((char*)d_ws + NEDGE * sizeof(unsigned));

    hipMemsetAsync(cnt, 0, M_CHK * sizeof(int), stream);
    setup_slots<<<(NEDGE + 255) / 256, 256, 0, stream>>>(chk, tbl, cnt);
    nsp_kernel<<<BATCH, TPB, 0, stream>>>(llr, vw, cw, tbl, out);
}

// Round 4
// 382.202 us; speedup vs baseline: 2.4219x; 1.0324x over previous
//
#include <hip/hip_runtime.h>

// NeuralSumProductModel: weighted sum-product LDPC decoder.
// N=8192 vars, M=4096 checks, DV=3, DC=6, ITERS=5, B=1024, E=24576.
// One block per batch row; thread t owns 24 contiguous edges = 8 variables.
// Check reduction WITHOUT atomics: setup kernel builds addr[e] = c*6 + slot;
// Phase A scatter-writes packed messages to lds_m[addr]; Phase A2 (4 checks/
// thread, c = t + k*1024 so lane stride = 6 words -> only 4-way conflicts)
// reduces 6 contiguous slots -> packed chk_tot; Phase B reads one packed word
// per edge and overwrites lds_m[addr] with the signed check message (same
// thread owns the slot -> no barrier needed before next Phase A reads it).
//
// Register budget note: 1024-thread blocks force 4 waves/EU -> 128 unified
// (arch+acc) VGPRs/wave, allocator splits 64+64. R2/R3 kept st[24]+te[24] in
// "registers" which overflowed to scratch (+127MB fetch, +103MB write, HBM-
// latency stalls). This version keeps only llr_v[8] + te-packed[12] in regs;
// per-edge state lives in lds_m. No scratch.

#define N_VARS 8192
#define M_CHK  4096
#define ITERS  5
#define BATCH  1024
#define NEDGE  (N_VARS * 3)     // 24576
#define TPB    1024
#define EPT    (NEDGE / TPB)    // 24 edges / thread
#define VPT    (N_VARS / TPB)   // 8 variables / thread
#define CPT    (M_CHK / TPB)    // 4 checks / thread

#define LOG2E_F 1.44269504f
#define LN2_F   0.69314718f
#define M_CLIP  39.863137f      // -log2(1e-12)
#define E_CLIP  0.99999988f     // float32(1 - 1e-7)

// packed edge message: bits[30:0] = m = -log2|tanh(x/2)| (>=0), bit31 = (x<0)
__device__ __forceinline__ float edge_msg(float x) {
    float a  = fabsf(x);
    float ee = __builtin_amdgcn_exp2f(-a * LOG2E_F);          // e^{-|x|}
    float m  = __builtin_amdgcn_logf(1.0f + ee) - __builtin_amdgcn_logf(1.0f - ee);
    m = fminf(m, M_CLIP);
    unsigned neg = (x < 0.0f) ? 0x80000000u : 0u;
    return __uint_as_float(__float_as_uint(m) | neg);
}

// c = addr/6 for addr < 32768 (exact): floor(addr*10923/65536)
__device__ __forceinline__ unsigned div6(unsigned a) {
    return (a * 10923u) >> 16;
}

// ---- setup: per-edge LDS slot addr = c*6 + rank-within-check
__global__ void setup_slots(const int* __restrict__ chk,
                            unsigned* __restrict__ tbl,
                            int* __restrict__ cnt) {
    int e = blockIdx.x * 256 + threadIdx.x;
    if (e < NEDGE) {
        int c = chk[e];
        int slot = atomicAdd(&cnt[c], 1);
        tbl[e] = (unsigned)(c * 6 + slot);    // < 24576, fits 16 bits
    }
}

__global__ __launch_bounds__(TPB, 4)
void nsp_kernel(const float* __restrict__ llr,
                const float* __restrict__ vw,
                const float* __restrict__ cw,
                const unsigned* __restrict__ tbl,
                float* __restrict__ out)
{
    __shared__ float    lds_m[NEDGE];     // 96 KB: per-edge state at c*6+slot
    __shared__ unsigned chk_tot[M_CHK];   // 16 KB: packed (S, parity)

    const int b  = blockIdx.x;
    const int t  = threadIdx.x;
    const int e0 = t * EPT;
    const int n0 = t * VPT;

    // llr for my 8 variables
    float llr_v[VPT];
    {
        const float4* p = (const float4*)(llr + (size_t)b * N_VARS + n0);
        float4 a = p[0], c = p[1];
        llr_v[0] = a.x; llr_v[1] = a.y; llr_v[2] = a.z; llr_v[3] = a.w;
        llr_v[4] = c.x; llr_v[5] = c.y; llr_v[6] = c.z; llr_v[7] = c.w;
    }

    // 16-bit LDS addrs for my 24 edges, packed 2/reg
    unsigned pa[EPT / 2];
    {
        const uint4* p = (const uint4*)(tbl + e0);
#pragma unroll
        for (int k = 0; k < EPT / 4; ++k) {
            uint4 v = p[k];
            pa[2 * k]     = v.x | (v.y << 16);
            pa[2 * k + 1] = v.z | (v.w << 16);
        }
    }
#define ADDR(e) ((pa[(e) >> 1] >> (((e) & 1) * 16)) & 0xFFFFu)

    for (int it = 0; it < ITERS; ++it) {
        // ---- Phase A: variable-node LOO + log-domain msg, scatter to lds_m
        if (it == 0) {
#pragma unroll
            for (int v = 0; v < VPT; ++v) {
                float p = edge_msg(llr_v[v]);   // ext==0: same msg on 3 edges
#pragma unroll
                for (int j = 0; j < 3; ++j)
                    lds_m[ADDR(3 * v + j)] = p;
            }
        } else {
            const float* cwr = cw + (size_t)(it - 1) * NEDGE + e0;
            const float* vwr = vw + (size_t)it * NEDGE + e0;
            float outb[VPT];
#pragma unroll
            for (int v = 0; v < VPT; ++v) {
                // r_j from prev Phase B (own slots, same thread wrote them)
                float r0 = lds_m[ADDR(3 * v)];
                float r1 = lds_m[ADDR(3 * v + 1)];
                float r2 = lds_m[ADDR(3 * v + 2)];
                float x0 = r0 * cwr[3 * v];
                float x1 = r1 * cwr[3 * v + 1];
                float x2 = r2 * cwr[3 * v + 2];
                float s  = x0 + x1 + x2;
                outb[v]  = s + llr_v[v];        // output row it-1 (fused)
#pragma unroll
                for (int j = 0; j < 3; ++j) {
                    int e = 3 * v + j;
                    float extj = (j == 0) ? x0 : (j == 1) ? x1 : x2;
                    float x = (s - extj) * vwr[e] + llr_v[v];
                    lds_m[ADDR(e)] = edge_msg(x);
                }
            }
            float* op = out + ((size_t)(it - 1) * BATCH + b) * N_VARS + n0;
            ((float4*)op)[0] = make_float4(outb[0], outb[1], outb[2], outb[3]);
            ((float4*)op)[1] = make_float4(outb[4], outb[5], outb[6], outb[7]);
        }
        __syncthreads();

        // ---- Phase A2: per-check reduction; c = t + k*1024 -> lane stride 6
#pragma unroll
        for (int k = 0; k < CPT; ++k) {
            int c = t + k * TPB;
            const float2* q = (const float2*)(lds_m + c * 6);   // 8B-aligned
            float2 q0 = q[0], q1 = q[1], q2 = q[2];
            unsigned u0 = __float_as_uint(q0.x), u1 = __float_as_uint(q0.y);
            unsigned u2 = __float_as_uint(q1.x), u3 = __float_as_uint(q1.y);
            unsigned u4 = __float_as_uint(q2.x), u5 = __float_as_uint(q2.y);
            float S = __uint_as_float(u0 & 0x7fffffffu)
                    + __uint_as_float(u1 & 0x7fffffffu)
                    + __uint_as_float(u2 & 0x7fffffffu)
                    + __uint_as_float(u3 & 0x7fffffffu)
                    + __uint_as_float(u4 & 0x7fffffffu)
                    + __uint_as_float(u5 & 0x7fffffffu);
            unsigned P = (u0 ^ u1 ^ u2 ^ u3 ^ u4 ^ u5) & 0x80000000u;
            chk_tot[c] = __float_as_uint(S) | P;   // S>=0 so bit31 free
        }
        __syncthreads();

        // ---- Phase B: per-edge LOO + 2*atanh; overwrite own lds_m slot
#pragma unroll
        for (int e = 0; e < EPT; ++e) {
            unsigned ad = ADDR(e);
            unsigned u  = __float_as_uint(lds_m[ad]);
            float m  = __uint_as_float(u & 0x7fffffffu);
            unsigned T = chk_tot[div6(ad)];
            float S  = __uint_as_float(T & 0x7fffffffu);
            unsigned P = (T ^ u) & 0x80000000u;      // LOO parity
            float E = __builtin_amdgcn_exp2f(m - S); // prod of other |t|
            E = fminf(E, E_CLIP);
            float r = LN2_F * (__builtin_amdgcn_logf(1.0f + E)
                             - __builtin_amdgcn_logf(1.0f - E)); // 2*atanh
            lds_m[ad] = __uint_as_float(__float_as_uint(r) ^ P);
        }
        // no barrier: next Phase A touches only this thread's own slots;
        // next Phase A2 (the next cross-thread reader) is behind barrier 1.
    }

    // ---- final output row: ext = msg * cnode_w[ITERS-1]
    {
        const float* cwr = cw + (size_t)(ITERS - 1) * NEDGE + e0;
        float outb[VPT];
#pragma unroll
        for (int v = 0; v < VPT; ++v) {
            float s = lds_m[ADDR(3 * v)]     * cwr[3 * v]
                    + lds_m[ADDR(3 * v + 1)] * cwr[3 * v + 1]
                    + lds_m[ADDR(3 * v + 2)] * cwr[3 * v + 2];
            outb[v] = s + llr_v[v];
        }
        float* op = out + ((size_t)(ITERS - 1) * BATCH + b) * N_VARS + n0;
        ((float4*)op)[0] = make_float4(outb[0], outb[1], outb[2], outb[3]);
        ((float4*)op)[1] = make_float4(outb[4], outb[5], outb[6], outb[7]);
    }
#undef ADDR
}

extern "C" void kernel_launch(void* const* d_in, const int* in_sizes, int n_in,
                              void* d_out, int out_size, void* d_ws, size_t ws_size,
                              hipStream_t stream) {
    const float* llr = (const float*)d_in[0];   // (B, N)
    const float* vw  = (const float*)d_in[1];   // (ITERS, E)
    const float* cw  = (const float*)d_in[2];   // (ITERS, E)
    // d_in[3] = var_idx (unused: edges are variable-major, var = e/3)
    const int*   chk = (const int*)d_in[4];     // (E,)
    float* out = (float*)d_out;                 // (ITERS, B, N) f32

    // ws layout: [0, 96KB) u32 tbl[NEDGE]; [96KB, +16KB) int cnt[M_CHK]
    unsigned* tbl = (unsigned*)d_ws;
    int*      cnt = (int*)((char*)d_ws + NEDGE * sizeof(unsigned));

    hipMemsetAsync(cnt, 0, M_CHK * sizeof(int), stream);
    setup_slots<<<(NEDGE + 255) / 256, 256, 0, stream>>>(chk, tbl, cnt);
    nsp_kernel<<<BATCH, TPB, 0, stream>>>(llr, vw, cw, tbl, out);
}